// Round 12
// baseline (319.038 us; speedup 1.0000x reference)
//
#include <hip/hip_runtime.h>
#include <math.h>

#pragma clang fp contract(off)

#define NB 16
#define NC 80
#define NTOT 17064
#define TOPK 1000
#define NBINS 8192
#define CAP 4096
#define MAXDET 100
#define NREP 4           // small-ws fallback histogram replicas
#define CNTSTRIDE 64     // u32 stride between per-batch counters = 256 B
#define CHUNK 128        // NMS staging chunk
#define G1 128           // pass-1 blocks per batch
#define NSEG 512         // G1 * 4 wave-segments per batch
#define SEGW 512         // entries per wave-segment (mean ~55 at gate 0.08)

struct Ptrs {
    const float* lg[5];
    const float* bb[5];
    const float* ct[5];
};

__device__ __forceinline__ void level_of(int n, int& l, int& hw, int& W,
                                         int& stride, int& half, int& HW) {
    if (n < 12800)      { l = 0; hw = n;         W = 128; stride = 8;   half = 4;  HW = 12800; }
    else if (n < 16000) { l = 1; hw = n - 12800; W = 64;  stride = 16;  half = 8;  HW = 3200;  }
    else if (n < 16800) { l = 2; hw = n - 16000; W = 32;  stride = 32;  half = 16; HW = 800;   }
    else if (n < 17008) { l = 3; hw = n - 16800; W = 16;  stride = 64;  half = 32; HW = 208;   }
    else                { l = 4; hw = n - 17008; W = 8;   stride = 128; half = 64; HW = 56;    }
}

// Fast HW sigmoid (v_exp_f32 + v_rcp_f32). |fast - exact| <= ~15 ulp on the
// comb product. Used for coarse gating/binning only; keys are always exact.
__device__ __forceinline__ float fast_sig(float x) {
    float e = __expf(-x);
    return __builtin_amdgcn_rcpf(1.0f + e);
}

// ---------------- pass 1: coarse-gated candidate append ---------------------
// Append (fast_bits<<32 | ~idx) for fast comb >= bits(0.08)-64 into a private
// per-(block,wave) segment: register cursor + ballot prefix — no LDS, no
// atomics, no barriers. Superset: exact comb >= 0.08 => fast >= bits(0.08)-15
// > gate => appended. Prefilter x > -2.47 (logit(0.08) = -2.442).
template<int HW4, int NF4, int LVOFF>
__device__ __forceinline__ void scan_level(const float* lgb, const float* ctb,
        int tid, int lane, int bx, int gx, unsigned FB_LO,
        unsigned long long* segp, unsigned& cur, unsigned long long ltmask) {
    for (int i0 = bx * 256; i0 < NF4; i0 += gx * 256) {
        int i = i0 + tid;
        bool f0 = false, f1 = false, f2 = false, f3 = false;
        unsigned long long k0 = 0, k1 = 0, k2 = 0, k3 = 0;
        if (i < NF4) {
            int c   = i / HW4;            // constant divisor -> magic mul
            int hwf = i - c * HW4;
            float4 v = *(const float4*)(lgb + c * (HW4 * 4) + hwf * 4);
            if (v.x > -2.47f || v.y > -2.47f || v.z > -2.47f || v.w > -2.47f) {
                float4 cv = *(const float4*)(ctb + hwf * 4);
                int nbase = LVOFF + hwf * 4;
#define DO_J(J, X, CT, F, K)                                                  \
                if ((X) > -2.47f) {                                           \
                    float cls = fast_sig(X);                                  \
                    float cen = fast_sig(CT);                                 \
                    unsigned bits = __float_as_uint(cls * cen);               \
                    if (bits >= FB_LO) {                                      \
                        unsigned idx = (unsigned)((nbase + (J)) * NC + c);    \
                        K = ((unsigned long long)bits << 32) |                \
                            (0xFFFFFFFFu - idx);                              \
                        F = true;                                             \
                    }                                                         \
                }
                DO_J(0, v.x, cv.x, f0, k0)
                DO_J(1, v.y, cv.y, f1, k1)
                DO_J(2, v.z, cv.z, f2, k2)
                DO_J(3, v.w, cv.w, f3, k3)
#undef DO_J
            }
        }
        unsigned long long m0 = __ballot(f0), m1 = __ballot(f1);
        unsigned long long m2 = __ballot(f2), m3 = __ballot(f3);
        if ((m0 | m1 | m2 | m3) == 0ULL) continue;   // wave-uniform skip
        unsigned t0 = (unsigned)__popcll(m0), t1 = (unsigned)__popcll(m1);
        unsigned t2 = (unsigned)__popcll(m2), t3 = (unsigned)__popcll(m3);
        if (f0) { unsigned pos = cur + (unsigned)__popcll(m0 & ltmask);                if (pos < SEGW) segp[pos] = k0; }
        if (f1) { unsigned pos = cur + t0 + (unsigned)__popcll(m1 & ltmask);           if (pos < SEGW) segp[pos] = k1; }
        if (f2) { unsigned pos = cur + t0 + t1 + (unsigned)__popcll(m2 & ltmask);      if (pos < SEGW) segp[pos] = k2; }
        if (f3) { unsigned pos = cur + t0 + t1 + t2 + (unsigned)__popcll(m3 & ltmask); if (pos < SEGW) segp[pos] = k3; }
        cur += t0 + t1 + t2 + t3;
    }
}

__global__ void __launch_bounds__(256) k_scoreF(Ptrs p, unsigned* segcnt,
                                                unsigned long long* segbuf) {
    int b = blockIdx.y, tid = threadIdx.x, bx = blockIdx.x, gx = gridDim.x;
    int lane = tid & 63, wv = tid >> 6;
    unsigned long long ltmask = (1ULL << lane) - 1ULL;
    unsigned FB_LO = __float_as_uint(0.08f) - 64u;
    unsigned long long* segp = segbuf + (((size_t)b * G1 + bx) * 4 + wv) * SEGW;
    unsigned cur = 0;

    scan_level<3200, 256000,     0>(p.lg[0] + (size_t)b * NC * 12800, p.ct[0] + (size_t)b * 12800, tid, lane, bx, gx, FB_LO, segp, cur, ltmask);
    scan_level< 800,  64000, 12800>(p.lg[1] + (size_t)b * NC * 3200,  p.ct[1] + (size_t)b * 3200,  tid, lane, bx, gx, FB_LO, segp, cur, ltmask);
    scan_level< 200,  16000, 16000>(p.lg[2] + (size_t)b * NC * 800,   p.ct[2] + (size_t)b * 800,   tid, lane, bx, gx, FB_LO, segp, cur, ltmask);
    scan_level<  52,   4160, 16800>(p.lg[3] + (size_t)b * NC * 208,   p.ct[3] + (size_t)b * 208,   tid, lane, bx, gx, FB_LO, segp, cur, ltmask);
    scan_level<  14,   1120, 17008>(p.lg[4] + (size_t)b * NC * 56,    p.ct[4] + (size_t)b * 56,    tid, lane, bx, gx, FB_LO, segp, cur, ltmask);

    if (lane == 0) segcnt[(size_t)b * NSEG + bx * 4 + wv] = cur;  // raw (overflow detectable)
}

// Fallback full-population conservative histogram (1024-thread, one block).
template<int HW4, int NF4>
__device__ __forceinline__ void histf_level(const float* lgb, const float* ctb,
                                            int tid, unsigned* hist) {
    for (int i0 = 0; i0 < NF4; i0 += 1024) {
        int i = i0 + tid;
        if (i < NF4) {
            int c   = i / HW4;
            int hwf = i - c * HW4;
            float4 v = *(const float4*)(lgb + c * (HW4 * 4) + hwf * 4);
            if (v.x > -2.95f || v.y > -2.95f || v.z > -2.95f || v.w > -2.95f) {
                float4 cv = *(const float4*)(ctb + hwf * 4);
                float xs[4] = {v.x, v.y, v.z, v.w};
                float cs[4] = {cv.x, cv.y, cv.z, cv.w};
#pragma unroll
                for (int j = 0; j < 4; ++j) {
                    float x = xs[j];
                    if (x > -2.95f) {
                        float cls = fast_sig(x);
                        if (cls > 0.04999f) {
                            bool in = true;
                            if (cls < 0.05001f)
                                in = (1.0f / (1.0f + expf(-x))) > 0.05f;
                            if (in) {
                                float cen = fast_sig(cs[j]);
                                unsigned bits = __float_as_uint(cls * cen);
                                unsigned cb = (bits > 32u) ? bits - 32u : 0u;
                                atomicAdd(&hist[cb >> 19], 1u);
                            }
                        }
                    }
                }
            }
        }
    }
}

// Shared exact-compact helper (fallbacks). Works for any (bx,gx) virtual-block
// decomposition with 256-thread groups; ballots/atomics are wave-scoped.
template<int HW4, int NF4, int LVOFF>
__device__ __forceinline__ void compact_level(const float* lgb, const float* ctb,
        int tid, int lane, int bx, int gx, unsigned Tb, float xpre,
        unsigned* cntb, unsigned long long* selb, unsigned long long ltmask) {
    for (int i0 = bx * 256; i0 < NF4; i0 += gx * 256) {
        int i = i0 + tid;
        bool f0 = false, f1 = false, f2 = false, f3 = false;
        unsigned long long k0 = 0, k1 = 0, k2 = 0, k3 = 0;
        if (i < NF4) {
            int c   = i / HW4;
            int hwf = i - c * HW4;
            float4 v = *(const float4*)(lgb + c * (HW4 * 4) + hwf * 4);
            if (v.x > xpre || v.y > xpre || v.z > xpre || v.w > xpre) {
                float4 cv = *(const float4*)(ctb + hwf * 4);
                int nbase = LVOFF + hwf * 4;
#define DO_J(J, X, CT, F, K)                                                  \
                if ((X) > xpre) {                                             \
                    float cls = 1.0f / (1.0f + expf(-(X)));                   \
                    if (cls > 0.05f) {                                        \
                        float cen = 1.0f / (1.0f + expf(-(CT)));              \
                        float comb = cls * cen;                               \
                        unsigned bits = __float_as_uint(comb);                \
                        if ((bits >> 19) >= Tb) {                             \
                            unsigned idx = (unsigned)((nbase + (J)) * NC + c);\
                            K = ((unsigned long long)bits << 32) |            \
                                (0xFFFFFFFFu - idx);                          \
                            F = true;                                         \
                        }                                                     \
                    }                                                         \
                }
                DO_J(0, v.x, cv.x, f0, k0)
                DO_J(1, v.y, cv.y, f1, k1)
                DO_J(2, v.z, cv.z, f2, k2)
                DO_J(3, v.w, cv.w, f3, k3)
#undef DO_J
            }
        }
        unsigned long long m0 = __ballot(f0), m1 = __ballot(f1);
        unsigned long long m2 = __ballot(f2), m3 = __ballot(f3);
        if ((m0 | m1 | m2 | m3) == 0ULL) continue;
        unsigned t0 = (unsigned)__popcll(m0), t1 = (unsigned)__popcll(m1);
        unsigned t2 = (unsigned)__popcll(m2), t3 = (unsigned)__popcll(m3);
        unsigned total = t0 + t1 + t2 + t3;
        int basep = 0;
        if (lane == 0) basep = (int)atomicAdd(cntb, total);
        basep = __shfl(basep, 0);
        if (f0) { int pos = basep + (int)__popcll(m0 & ltmask);                       if (pos < CAP) selb[pos] = k0; }
        if (f1) { int pos = basep + (int)t0 + (int)__popcll(m1 & ltmask);             if (pos < CAP) selb[pos] = k1; }
        if (f2) { int pos = basep + (int)(t0 + t1) + (int)__popcll(m2 & ltmask);      if (pos < CAP) selb[pos] = k2; }
        if (f3) { int pos = basep + (int)(t0 + t1 + t2) + (int)__popcll(m3 & ltmask); if (pos < CAP) selb[pos] = k3; }
    }
}

// ---------------- fused threshold + filter (one block/batch, 1024 thr) ------
// All appended entries have comb in [0.08, 1) => local bins 0..59 relative to
// BINBASE = bits(0.08)>>19. Per-wave 64-bin histograms (no cross-wave atomic
// contention), tid0 suffix scan -> T. ok := no overflow AND suffix(local 1)
// >= TOPK  =>  T identical to the full-population conservative histogram's T
// (boundary bin 0 excluded; all bins >= 1 fully captured by the append gate).
// Then filter in-kernel: survivors (fast >= (T<<19)-32) get exact sigmoid
// recompute; exact bin >= T -> exact key compacted into sel. Fallback (!ok,
// never taken for this data): full-population 8192-bin histogram + full
// compact sweep inside this block.
__global__ void __launch_bounds__(1024) k_pick(Ptrs p, const unsigned* segcnt,
                                               const unsigned long long* segbuf,
                                               unsigned* cnt2, unsigned long long* sel) {
    __shared__ unsigned wh[16][64];     // per-wave 64-bin hist (4 KiB)
    __shared__ unsigned red[64];
    __shared__ unsigned fullh[NBINS];   // fallback only (32 KiB)
    __shared__ int s_flags, s_T, s_ok;
    int b = blockIdx.x, tid = threadIdx.x, lane = tid & 63, wv = tid >> 6;
    if (tid == 0) { s_flags = 0; cnt2[(size_t)b * CNTSTRIDE] = 0; }
    ((unsigned*)wh)[tid] = 0;           // 16*64 == 1024
    __syncthreads();

    const int BINBASE = (int)(__float_as_uint(0.08f) >> 19);
    bool ovf = false;
    for (int sg = wv; sg < NSEG; sg += 16) {
        unsigned cnt = segcnt[(size_t)b * NSEG + sg];
        if (cnt > SEGW) { ovf = true; cnt = SEGW; }
        const unsigned long long* src = segbuf + ((size_t)b * NSEG + sg) * SEGW;
        for (int i = lane; i < (int)cnt; i += 64) {
            unsigned bits = (unsigned)(src[i] >> 32);
            unsigned cb = (bits > 32u) ? bits - 32u : 0u;
            int lb = (int)(cb >> 19) - BINBASE;
            lb = (lb < 0) ? 0 : ((lb > 63) ? 63 : lb);
            atomicAdd(&wh[wv][lb], 1u);
        }
    }
    if (ovf) atomicOr(&s_flags, 1);
    __syncthreads();
    if (tid < 64) {
        unsigned s = 0;
#pragma unroll
        for (int w = 0; w < 16; ++w) s += wh[w][tid];
        red[tid] = s;
    }
    __syncthreads();
    if (tid == 0) {
        unsigned total = 0;
        for (int i = 0; i < 64; ++i) total += red[i];
        unsigned suf1 = total - red[0];
        unsigned run = 0; int Tl = 0;
        for (int i = 63; i >= 0; --i) {
            run += red[i];
            if (run >= TOPK) { Tl = i; break; }
        }
        s_ok = ((s_flags & 1) == 0) && (suf1 >= TOPK);
        s_T = Tl + BINBASE;
    }
    __syncthreads();

    unsigned* cntb = cnt2 + (size_t)b * CNTSTRIDE;
    unsigned long long* selb = sel + (size_t)b * CAP;
    unsigned long long ltmask = (1ULL << lane) - 1ULL;
    unsigned Tb = (unsigned)s_T;

    if (s_ok) {
        unsigned fmin = (Tb << 19) - 32u;          // Tb >= BINBASE+1: no underflow
        for (int sg = wv; sg < NSEG; sg += 16) {
            unsigned cnt = segcnt[(size_t)b * NSEG + sg];
            if (cnt > SEGW) cnt = SEGW;
            const unsigned long long* src = segbuf + ((size_t)b * NSEG + sg) * SEGW;
            for (unsigned i0 = 0; i0 < cnt; i0 += 64) {   // uniform wave bound
                unsigned i = i0 + (unsigned)lane;
                bool f = false;
                unsigned long long key = 0;
                if (i < cnt) {
                    unsigned long long e = src[i];
                    if ((unsigned)(e >> 32) >= fmin) {
                        unsigned idx = 0xFFFFFFFFu - (unsigned)(e & 0xFFFFFFFFu);
                        int n = idx / NC, c = idx - n * NC;
                        int l, hw, W, stride, half, HW;
                        level_of(n, l, hw, W, stride, half, HW);
                        float x  = p.lg[l][(size_t)b * NC * HW + (size_t)c * HW + hw];
                        float ct = p.ct[l][(size_t)b * HW + hw];
                        float cls = 1.0f / (1.0f + expf(-x));
                        if (cls > 0.05f) {
                            float cen = 1.0f / (1.0f + expf(-ct));
                            unsigned be = __float_as_uint(cls * cen);
                            if ((be >> 19) >= Tb) {
                                key = ((unsigned long long)be << 32) | (e & 0xFFFFFFFFULL);
                                f = true;
                            }
                        }
                    }
                }
                unsigned long long mk = __ballot(f);
                if (mk) {
                    unsigned nw = (unsigned)__popcll(mk);
                    int basep = 0;
                    if (lane == 0) basep = (int)atomicAdd(cntb, nw);
                    basep = __shfl(basep, 0);
                    if (f) {
                        int pos = basep + (int)__popcll(mk & ltmask);
                        if (pos < CAP) selb[pos] = key;
                    }
                }
            }
        }
    } else {
        // full-population fallback (never taken for this data)
        for (int i = tid; i < NBINS; i += 1024) fullh[i] = 0;
        __syncthreads();
        histf_level<3200, 256000>(p.lg[0] + (size_t)b * NC * 12800, p.ct[0] + (size_t)b * 12800, tid, fullh);
        histf_level< 800,  64000>(p.lg[1] + (size_t)b * NC * 3200,  p.ct[1] + (size_t)b * 3200,  tid, fullh);
        histf_level< 200,  16000>(p.lg[2] + (size_t)b * NC * 800,   p.ct[2] + (size_t)b * 800,   tid, fullh);
        histf_level<  52,   4160>(p.lg[3] + (size_t)b * NC * 208,   p.ct[3] + (size_t)b * 208,   tid, fullh);
        histf_level<  14,   1120>(p.lg[4] + (size_t)b * NC * 56,    p.ct[4] + (size_t)b * 56,    tid, fullh);
        __syncthreads();
        if (tid == 0) {
            unsigned run = 0; int Tf2 = 0;
            for (int i = NBINS - 1; i >= 0; --i) {
                run += fullh[i];
                if (run >= TOPK) { Tf2 = i; break; }
            }
            s_T = Tf2;
        }
        __syncthreads();
        Tb = (unsigned)s_T;
        float mthr = __uint_as_float(Tb << 19);
        float xpre = -2.95f;
        if (mthr > 1e-37f && mthr < 1.0f) {
            float lm = logf(mthr / (1.0f - mthr)) - 0.01f;
            if (lm > xpre) xpre = lm;
        }
        int vbx = tid >> 8, vtid = tid & 255;      // 4 virtual 256-thread blocks
        compact_level<3200, 256000,     0>(p.lg[0] + (size_t)b * NC * 12800, p.ct[0] + (size_t)b * 12800, vtid, lane, vbx, 4, Tb, xpre, cntb, selb, ltmask);
        compact_level< 800,  64000, 12800>(p.lg[1] + (size_t)b * NC * 3200,  p.ct[1] + (size_t)b * 3200,  vtid, lane, vbx, 4, Tb, xpre, cntb, selb, ltmask);
        compact_level< 200,  16000, 16000>(p.lg[2] + (size_t)b * NC * 800,   p.ct[2] + (size_t)b * 800,   vtid, lane, vbx, 4, Tb, xpre, cntb, selb, ltmask);
        compact_level<  52,   4160, 16800>(p.lg[3] + (size_t)b * NC * 208,   p.ct[3] + (size_t)b * 208,   vtid, lane, vbx, 4, Tb, xpre, cntb, selb, ltmask);
        compact_level<  14,   1120, 17008>(p.lg[4] + (size_t)b * NC * 56,    p.ct[4] + (size_t)b * 56,    vtid, lane, vbx, 4, Tb, xpre, cntb, selb, ltmask);
    }
}

// ---------------- small-ws fallback pipeline (round-9 kernels) --------------
template<int HW4, int NF4>
__device__ __forceinline__ void hist_level(const float* lgb, const float* ctb,
                                           int tid, int bx, int gx, unsigned* lh) {
    for (int i0 = bx * 256; i0 < NF4; i0 += gx * 256) {
        int i = i0 + tid;
        if (i < NF4) {
            int c   = i / HW4;
            int hwf = i - c * HW4;
            float4 v  = *(const float4*)(lgb + c * (HW4 * 4) + hwf * 4);
            if (v.x > -2.95f || v.y > -2.95f || v.z > -2.95f || v.w > -2.95f) {
                float4 cv = *(const float4*)(ctb + hwf * 4);
                float xs[4] = {v.x, v.y, v.z, v.w};
                float cs[4] = {cv.x, cv.y, cv.z, cv.w};
#pragma unroll
                for (int j = 0; j < 4; ++j) {
                    float x = xs[j];
                    if (x > -2.95f) {
                        float cls = fast_sig(x);
                        if (cls > 0.04999f) {
                            bool in = true;
                            if (cls < 0.05001f)
                                in = (1.0f / (1.0f + expf(-x))) > 0.05f;
                            if (in) {
                                float cen = fast_sig(cs[j]);
                                unsigned bits = __float_as_uint(cls * cen);
                                unsigned cb = (bits > 32u) ? bits - 32u : 0u;
                                atomicAdd(&lh[cb >> 19], 1u);
                            }
                        }
                    }
                }
            }
        }
    }
}

__global__ void __launch_bounds__(256) k_histA(Ptrs p, unsigned* hist) {
    __shared__ unsigned lh[NBINS];
    int b = blockIdx.y, tid = threadIdx.x, bx = blockIdx.x, gx = gridDim.x;
    for (int i = tid; i < NBINS; i += 256) lh[i] = 0;
    __syncthreads();
    hist_level<3200, 256000>(p.lg[0] + (size_t)b * NC * 12800, p.ct[0] + (size_t)b * 12800, tid, bx, gx, lh);
    hist_level< 800,  64000>(p.lg[1] + (size_t)b * NC * 3200,  p.ct[1] + (size_t)b * 3200,  tid, bx, gx, lh);
    hist_level< 200,  16000>(p.lg[2] + (size_t)b * NC * 800,   p.ct[2] + (size_t)b * 800,   tid, bx, gx, lh);
    hist_level<  52,   4160>(p.lg[3] + (size_t)b * NC * 208,   p.ct[3] + (size_t)b * 208,   tid, bx, gx, lh);
    hist_level<  14,   1120>(p.lg[4] + (size_t)b * NC * 56,    p.ct[4] + (size_t)b * 56,    tid, bx, gx, lh);
    __syncthreads();
    unsigned* h = hist + ((size_t)(bx & (NREP - 1)) * NB + b) * NBINS;
    for (int i = tid; i < NBINS; i += 256) {
        unsigned v = lh[i];
        if (v) atomicAdd(&h[i], v);
    }
}

__global__ void __launch_bounds__(256) k_thresh(const unsigned* hist, unsigned* T) {
    __shared__ unsigned hl[NBINS];
    __shared__ unsigned wtot[4];
    __shared__ int Tf;
    int b = blockIdx.x, tid = threadIdx.x, lane = tid & 63, wv = tid >> 6;
    if (tid == 0) Tf = 0;
    for (int i = tid; i < NBINS; i += 256) {
        unsigned s = 0;
        for (int r = 0; r < NREP; ++r)
            s += hist[((size_t)r * NB + b) * NBINS + i];
        hl[i] = s;
    }
    __syncthreads();
    int base = tid * 32;
    unsigned mysum = 0;
#pragma unroll
    for (int i = 0; i < 32; ++i) mysum += hl[base + i];
    unsigned incl = mysum;
#pragma unroll
    for (int off = 1; off < 64; off <<= 1) {
        unsigned v = __shfl_down(incl, off);
        if (lane + off < 64) incl += v;
    }
    if (lane == 0) wtot[wv] = incl;
    __syncthreads();
    unsigned above = 0;
    for (int w = wv + 1; w < 4; ++w) above += wtot[w];
    unsigned sufincl = incl + above;
    unsigned excl = sufincl - mysum;
    if (excl < TOPK && sufincl >= TOPK) {
        unsigned running = excl;
        for (int bin = base + 31; bin >= base; --bin) {
            running += hl[bin];
            if (running >= TOPK) { Tf = bin; break; }
        }
    }
    __syncthreads();
    if (tid == 0) T[b] = (unsigned)Tf;
}

__global__ void __launch_bounds__(256) k_compactB(Ptrs p, const unsigned* T,
                                                  unsigned* cnt2, unsigned long long* sel) {
    int b = blockIdx.y, tid = threadIdx.x, lane = tid & 63;
    int bx = blockIdx.x, gx = gridDim.x;
    unsigned Tb = T[b];
    float mthr = __uint_as_float(Tb << 19);
    float xpre = -2.95f;
    if (mthr > 1e-37f && mthr < 1.0f) {
        float lm = logf(mthr / (1.0f - mthr)) - 0.01f;
        if (lm > xpre) xpre = lm;
    }
    unsigned long long ltmask = (1ULL << lane) - 1ULL;
    unsigned* cntb = cnt2 + (size_t)b * CNTSTRIDE;
    unsigned long long* selb = sel + (size_t)b * CAP;
    compact_level<3200, 256000,     0>(p.lg[0] + (size_t)b * NC * 12800, p.ct[0] + (size_t)b * 12800, tid, lane, bx, gx, Tb, xpre, cntb, selb, ltmask);
    compact_level< 800,  64000, 12800>(p.lg[1] + (size_t)b * NC * 3200,  p.ct[1] + (size_t)b * 3200,  tid, lane, bx, gx, Tb, xpre, cntb, selb, ltmask);
    compact_level< 200,  16000, 16000>(p.lg[2] + (size_t)b * NC * 800,   p.ct[2] + (size_t)b * 800,   tid, lane, bx, gx, Tb, xpre, cntb, selb, ltmask);
    compact_level<  52,   4160, 16800>(p.lg[3] + (size_t)b * NC * 208,   p.ct[3] + (size_t)b * 208,   tid, lane, bx, gx, Tb, xpre, cntb, selb, ltmask);
    compact_level<  14,   1120, 17008>(p.lg[4] + (size_t)b * NC * 56,    p.ct[4] + (size_t)b * 56,    tid, lane, bx, gx, Tb, xpre, cntb, selb, ltmask);
}

// ---------------- rank + decode (distributed across CUs) --------------------
__global__ void __launch_bounds__(256) k_rankdec(Ptrs p, const unsigned* cnt,
                                                 const unsigned long long* sel,
                                                 const float* im_info, float* cand) {
    __shared__ __align__(16) unsigned long long keys[CAP];
    int b = blockIdx.y, tid = threadIdx.x;
    unsigned M = cnt[(size_t)b * CNTSTRIDE];
    if (M > CAP) M = CAP;
    int s0 = blockIdx.x * 256;
    if (s0 >= (int)M) return;
    int Mpad = (int)((M + 1u) & ~1u);
    for (int i = tid; i < Mpad; i += 256)
        keys[i] = (i < (int)M) ? sel[(size_t)b * CAP + i] : 0ULL;
    __syncthreads();

    int s = s0 + tid;
    if (s >= (int)M) return;
    unsigned long long k = keys[s];
    int rank = 0;
    for (int j = 0; j < Mpad; j += 2) {
        ulonglong2 kk = *(const ulonglong2*)&keys[j];   // wave-broadcast b128
        rank += (kk.x > k) ? 1 : 0;
        rank += (kk.y > k) ? 1 : 0;
    }
    if (rank >= TOPK) return;

    float Him = im_info[b * 2 + 0], Wim = im_info[b * 2 + 1];
    float xmax = Wim - 1.0f, ymax = Him - 1.0f;
    unsigned sb = (unsigned)(k >> 32);
    unsigned idx = 0xFFFFFFFFu - (unsigned)(k & 0xFFFFFFFFu);
    float val = __uint_as_float(sb);
    int n = idx / NC, c = idx - n * NC;
    int l, hw, W, stride, half, HW;
    level_of(n, l, hw, W, stride, half, HW);
    int wx = hw % W, hy = hw / W;
    float locx = (float)(wx * stride + half);
    float locy = (float)(hy * stride + half);
    const float* bb = p.bb[l] + (size_t)b * 4 * HW + hw;
    float r0 = bb[0], r1 = bb[(size_t)HW], r2 = bb[(size_t)2 * HW], r3 = bb[(size_t)3 * HW];
    float x1 = locx - r0, y1 = locy - r1, x2 = locx + r2, y2 = locy + r3;
    x1 = fminf(fmaxf(x1, 0.f), xmax);
    y1 = fminf(fmaxf(y1, 0.f), ymax);
    x2 = fminf(fmaxf(x2, 0.f), xmax);
    y2 = fminf(fmaxf(y2, 0.f), ymax);
    float scv = sqrtf(val + 1e-12f);
    float off = (float)c * 10000.0f;
    float a0 = x1 + off, a1 = y1 + off, a2 = x2 + off, a3 = y2 + off;
    float area = fmaxf(a2 - a0, 0.f) * fmaxf(a3 - a1, 0.f);
    float* dst = cand + ((size_t)b * TOPK + rank) * 12;
    *(float4*)(dst + 0) = make_float4(x1, y1, x2, y2);
    *(float4*)(dst + 4) = make_float4(a0, a1, a2, a3);
    *(float4*)(dst + 8) = make_float4(area, scv, (float)c, 0.f);
}

// ---------------- scan-NMS (one wave per batch) -----------------------------
__global__ void __launch_bounds__(64) k_nms(const unsigned* cnt, const float* cand,
                                            float* out) {
    __shared__ float4 s_ob[CHUNK], s_nb[CHUNK], s_ms[CHUNK];
    int b = blockIdx.x, lane = threadIdx.x;
    unsigned M = cnt[(size_t)b * CNTSTRIDE];
    if (M > CAP) M = CAP;
    int ncand = (int)M < TOPK ? (int)M : TOPK;
    const float* src = cand + (size_t)b * TOPK * 12;
    float* ob = out + (size_t)b * MAXDET * 6;

    int na = 0;
    float4 a0b = make_float4(0.f, 0.f, 0.f, 0.f);
    float4 a1b = make_float4(0.f, 0.f, 0.f, 0.f);
    float a0a = 0.f, a1a = 0.f;

    for (int base = 0; base < ncand && na < MAXDET; base += CHUNK) {
        int cn = ncand - base; if (cn > CHUNK) cn = CHUNK;
        for (int cidx = lane; cidx < cn; cidx += 64) {
            const float* s = src + (size_t)(base + cidx) * 12;
            s_ob[cidx] = *(const float4*)(s + 0);
            s_nb[cidx] = *(const float4*)(s + 4);
            s_ms[cidx] = *(const float4*)(s + 8);
        }
        __syncthreads();
        for (int r = 0; r < cn && na < MAXDET; ++r) {
            float4 cb = s_nb[r];
            float ca = s_ms[r].x;
            bool sup = false;
            if (lane < na) {
                float xx1 = fmaxf(a0b.x, cb.x);
                float yy1 = fmaxf(a0b.y, cb.y);
                float xx2 = fminf(a0b.z, cb.z);
                float yy2 = fminf(a0b.w, cb.w);
                float inter = fmaxf(xx2 - xx1, 0.f) * fmaxf(yy2 - yy1, 0.f);
                float iou = inter / (((a0a + ca) - inter) + 1e-9f);
                sup = (iou >= 0.6f);
            }
            if (lane + 64 < na) {
                float xx1 = fmaxf(a1b.x, cb.x);
                float yy1 = fmaxf(a1b.y, cb.y);
                float xx2 = fminf(a1b.z, cb.z);
                float yy2 = fminf(a1b.w, cb.w);
                float inter = fmaxf(xx2 - xx1, 0.f) * fmaxf(yy2 - yy1, 0.f);
                float iou = inter / (((a1a + ca) - inter) + 1e-9f);
                sup |= (iou >= 0.6f);
            }
            if (__ballot(sup) == 0ULL) {
                if (lane == (na & 63)) {
                    if (na < 64) { a0b = cb; a0a = ca; }
                    else         { a1b = cb; a1a = ca; }
                }
                if (lane == 0) {
                    float4 o4 = s_ob[r]; float4 m4 = s_ms[r];
                    ob[na * 6 + 0] = o4.x; ob[na * 6 + 1] = o4.y;
                    ob[na * 6 + 2] = o4.z; ob[na * 6 + 3] = o4.w;
                    ob[na * 6 + 4] = m4.y; ob[na * 6 + 5] = m4.z;
                }
                ++na;
            }
        }
        __syncthreads();
    }
    for (int q = na * 6 + lane; q < MAXDET * 6; q += 64)
        ob[q] = 0.f;
}

extern "C" void kernel_launch(void* const* d_in, const int* in_sizes, int n_in,
                              void* d_out, int out_size, void* d_ws, size_t ws_size,
                              hipStream_t stream) {
    Ptrs p;
    for (int l = 0; l < 5; ++l) {
        p.lg[l] = (const float*)d_in[3 * l + 0];
        p.bb[l] = (const float*)d_in[3 * l + 1];
        p.ct[l] = (const float*)d_in[3 * l + 2];
    }
    const float* im_info = (const float*)d_in[15];
    float* out = (float*)d_out;
    unsigned char* w = (unsigned char*)d_ws;

    if (ws_size >= (size_t)34883584) {
        // big path: segcnt | cnt2 | sel | cand | segbuf — no memset needed
        unsigned* segcnt           = (unsigned*)(w);                    // 32768
        unsigned* cnt2             = (unsigned*)(w + 32768);            // 4096
        unsigned long long* sel    = (unsigned long long*)(w + 36864);  // 524288
        float* cand                = (float*)(w + 561152);              // 768000
        unsigned long long* segbuf = (unsigned long long*)(w + 1329152);// 33554432

        k_scoreF<<<dim3(G1, NB), 256, 0, stream>>>(p, segcnt, segbuf);
        k_pick<<<NB, 1024, 0, stream>>>(p, segcnt, segbuf, cnt2, sel);
        k_rankdec<<<dim3(16, NB), 256, 0, stream>>>(p, cnt2, sel, im_info, cand);
        k_nms<<<NB, 64, 0, stream>>>(cnt2, cand, out);
    } else {
        // small-ws fallback: round-9 pipeline
        unsigned* hist          = (unsigned*)(w);                       // 2097152
        unsigned* cnt2          = (unsigned*)(w + 2097152);             // 4096
        unsigned* T             = (unsigned*)(w + 2101248);             // 256
        unsigned long long* sel = (unsigned long long*)(w + 2101504);   // 524288
        float* cand             = (float*)(w + 2625792);                // 768000

        hipMemsetAsync(w, 0, 2101504, stream);
        k_histA<<<dim3(64, NB), 256, 0, stream>>>(p, hist);
        k_thresh<<<NB, 256, 0, stream>>>(hist, T);
        k_compactB<<<dim3(128, NB), 256, 0, stream>>>(p, T, cnt2, sel);
        k_rankdec<<<dim3(16, NB), 256, 0, stream>>>(p, cnt2, sel, im_info, cand);
        k_nms<<<NB, 64, 0, stream>>>(cnt2, cand, out);
    }
}

// Round 13
// 238.786 us; speedup vs baseline: 1.3361x; 1.3361x over previous
//
#include <hip/hip_runtime.h>
#include <math.h>

#pragma clang fp contract(off)

#define NB 16
#define NC 80
#define NTOT 17064
#define TOPK 1000
#define NBINS 8192
#define CAP 4096
#define MAXDET 100
#define CNTSTRIDE 64     // u32 stride between per-batch counters = 256 B
#define CHUNK 128        // NMS staging chunk
#define GH 128           // hist/compact blocks per batch

struct Ptrs {
    const float* lg[5];
    const float* bb[5];
    const float* ct[5];
};

__device__ __forceinline__ void level_of(int n, int& l, int& hw, int& W,
                                         int& stride, int& half, int& HW) {
    if (n < 12800)      { l = 0; hw = n;         W = 128; stride = 8;   half = 4;  HW = 12800; }
    else if (n < 16000) { l = 1; hw = n - 12800; W = 64;  stride = 16;  half = 8;  HW = 3200;  }
    else if (n < 16800) { l = 2; hw = n - 16000; W = 32;  stride = 32;  half = 16; HW = 800;   }
    else if (n < 17008) { l = 3; hw = n - 16800; W = 16;  stride = 64;  half = 32; HW = 208;   }
    else                { l = 4; hw = n - 17008; W = 8;   stride = 128; half = 64; HW = 56;    }
}

// Fast HW sigmoid (v_exp_f32 + v_rcp_f32). |fast - exact| <= ~15 ulp on the
// comb product. Used for gating/binning only; keys are always exact.
__device__ __forceinline__ float fast_sig(float x) {
    float e = __expf(-x);
    return __builtin_amdgcn_rcpf(1.0f + e);
}

// ---------------- pass 1: gated 64-bin histogram (x2-unrolled sweep) --------
// Gate: fast comb bits >= bits(0.08)-64. In-gate => exact cls >= exact comb
// >= 0.0798 > 0.05 (membership automatic, no guard band). Conservative local
// bin lb = ((bits-32)>>19)-BINBASE: any element whose conservative bin is
// >= BINBASE+1 has bits >= ((BINBASE+1)<<19)+32 > gate AND x > -2.45 > -2.47
// => counted. So for all bins >= BINBASE+1 the gated histogram EQUALS the
// full-population conservative histogram (round-9 semantics). k_thresh's
// ok-check guarantees T lands in that range.
#define HG_ELEM(X, CT)                                                        \
    if ((X) > -2.47f) {                   /* logit(0.08) = -2.442 */          \
        float cls = fast_sig(X);                                              \
        float cen = fast_sig(CT);                                             \
        unsigned bits = __float_as_uint(cls * cen);                           \
        if (bits >= FB_LO) {                                                  \
            int lb = (int)((bits - 32u) >> 19) - BINBASE;                     \
            lb = (lb < 0) ? 0 : ((lb > 63) ? 63 : lb);                        \
            atomicAdd(&whv[lb], 1u);                                          \
        }                                                                     \
    }

template<int HW4, int NF4>
__device__ __forceinline__ void histg_level(const float* lgb, const float* ctb,
        int tid, int bx, int gx, unsigned FB_LO, int BINBASE, unsigned* whv) {
    for (int i0 = bx * 512; i0 < NF4; i0 += gx * 512) {
        int ia = i0 + tid, ib = i0 + 256 + tid;
        bool la = ia < NF4, lb2 = ib < NF4;
        float4 va = make_float4(-9.f, -9.f, -9.f, -9.f);
        float4 vb = make_float4(-9.f, -9.f, -9.f, -9.f);
        int hwa = 0, hwb = 0;
        if (la) {
            int c = ia / HW4; hwa = ia - c * HW4;
            va = *(const float4*)(lgb + c * (HW4 * 4) + hwa * 4);
        }
        if (lb2) {
            int c = ib / HW4; hwb = ib - c * HW4;
            vb = *(const float4*)(lgb + c * (HW4 * 4) + hwb * 4);
        }
        if (va.x > -2.47f || va.y > -2.47f || va.z > -2.47f || va.w > -2.47f) {
            float4 cv = *(const float4*)(ctb + hwa * 4);
            HG_ELEM(va.x, cv.x) HG_ELEM(va.y, cv.y)
            HG_ELEM(va.z, cv.z) HG_ELEM(va.w, cv.w)
        }
        if (vb.x > -2.47f || vb.y > -2.47f || vb.z > -2.47f || vb.w > -2.47f) {
            float4 cv = *(const float4*)(ctb + hwb * 4);
            HG_ELEM(vb.x, cv.x) HG_ELEM(vb.y, cv.y)
            HG_ELEM(vb.z, cv.z) HG_ELEM(vb.w, cv.w)
        }
    }
}
#undef HG_ELEM

__global__ void __launch_bounds__(256) k_histB(Ptrs p, unsigned* hist, unsigned* cnt2) {
    __shared__ unsigned wh[4][64];   // per-wave 64-bin hist, 1 KiB
    int b = blockIdx.y, tid = threadIdx.x, bx = blockIdx.x, gx = gridDim.x;
    int wv = tid >> 6;
    if (bx == 0 && tid == 0) cnt2[(size_t)b * CNTSTRIDE] = 0;   // replaces memset
    ((unsigned*)wh)[tid] = 0;        // 256 == 4*64
    __syncthreads();
    unsigned FB_LO = __float_as_uint(0.08f) - 64u;
    int BINBASE = (int)(__float_as_uint(0.08f) >> 19);
    unsigned* whv = wh[wv];

    histg_level<3200, 256000>(p.lg[0] + (size_t)b * NC * 12800, p.ct[0] + (size_t)b * 12800, tid, bx, gx, FB_LO, BINBASE, whv);
    histg_level< 800,  64000>(p.lg[1] + (size_t)b * NC * 3200,  p.ct[1] + (size_t)b * 3200,  tid, bx, gx, FB_LO, BINBASE, whv);
    histg_level< 200,  16000>(p.lg[2] + (size_t)b * NC * 800,   p.ct[2] + (size_t)b * 800,   tid, bx, gx, FB_LO, BINBASE, whv);
    histg_level<  52,   4160>(p.lg[3] + (size_t)b * NC * 208,   p.ct[3] + (size_t)b * 208,   tid, bx, gx, FB_LO, BINBASE, whv);
    histg_level<  14,   1120>(p.lg[4] + (size_t)b * NC * 56,    p.ct[4] + (size_t)b * 56,    tid, bx, gx, FB_LO, BINBASE, whv);

    __syncthreads();
    if (tid < 64) {                  // per-block private slot: plain store, no atomics
        unsigned s = wh[0][tid] + wh[1][tid] + wh[2][tid] + wh[3][tid];
        hist[((size_t)b * GH + bx) * 64 + tid] = s;
    }
}

// Fallback full-population conservative histogram (round-9 semantics; only
// runs if the gated ok-check fails — never for this data).
template<int HW4, int NF4>
__device__ __forceinline__ void histf_level(const float* lgb, const float* ctb,
                                            int tid, unsigned* hist) {
    for (int i0 = 0; i0 < NF4; i0 += 256) {
        int i = i0 + tid;
        if (i < NF4) {
            int c = i / HW4, hwf = i - c * HW4;
            float4 v = *(const float4*)(lgb + c * (HW4 * 4) + hwf * 4);
            if (v.x > -2.95f || v.y > -2.95f || v.z > -2.95f || v.w > -2.95f) {
                float4 cv = *(const float4*)(ctb + hwf * 4);
                float xs[4] = {v.x, v.y, v.z, v.w};
                float cs[4] = {cv.x, cv.y, cv.z, cv.w};
#pragma unroll
                for (int j = 0; j < 4; ++j) {
                    float x = xs[j];
                    if (x > -2.95f) {
                        float cls = fast_sig(x);
                        if (cls > 0.04999f) {
                            bool in = true;
                            if (cls < 0.05001f)
                                in = (1.0f / (1.0f + expf(-x))) > 0.05f;
                            if (in) {
                                float cen = fast_sig(cs[j]);
                                unsigned bits = __float_as_uint(cls * cen);
                                unsigned cb = (bits > 32u) ? bits - 32u : 0u;
                                atomicAdd(&hist[cb >> 19], 1u);
                            }
                        }
                    }
                }
            }
        }
    }
}

// ---------------- threshold from gated histogram + verified ok-check --------
__global__ void __launch_bounds__(256) k_thresh(Ptrs p, const unsigned* hist,
                                                unsigned* T) {
    __shared__ unsigned part[4][64];
    __shared__ unsigned red[64];
    __shared__ unsigned fullh[NBINS];   // fallback only (32 KiB)
    __shared__ int s_T, s_ok;
    int b = blockIdx.x, tid = threadIdx.x;
    int bin = tid & 63, grp = tid >> 6;
    int BINBASE = (int)(__float_as_uint(0.08f) >> 19);

    unsigned s = 0;
    for (int blk = grp; blk < GH; blk += 4)
        s += hist[((size_t)b * GH + blk) * 64 + bin];   // coalesced per 64-group
    part[grp][bin] = s;
    __syncthreads();
    if (tid < 64) red[tid] = part[0][tid] + part[1][tid] + part[2][tid] + part[3][tid];
    __syncthreads();
    if (tid == 0) {
        unsigned suf1 = 0;
        for (int i = 1; i < 64; ++i) suf1 += red[i];
        unsigned run = 0; int Tl = 0;
        for (int i = 63; i >= 1; --i) {
            run += red[i];
            if (run >= TOPK) { Tl = i; break; }
        }
        s_ok = (suf1 >= TOPK);
        s_T = Tl + BINBASE;
    }
    __syncthreads();

    if (!s_ok) {                        // never taken for this data
        for (int i = tid; i < NBINS; i += 256) fullh[i] = 0;
        __syncthreads();
        histf_level<3200, 256000>(p.lg[0] + (size_t)b * NC * 12800, p.ct[0] + (size_t)b * 12800, tid, fullh);
        histf_level< 800,  64000>(p.lg[1] + (size_t)b * NC * 3200,  p.ct[1] + (size_t)b * 3200,  tid, fullh);
        histf_level< 200,  16000>(p.lg[2] + (size_t)b * NC * 800,   p.ct[2] + (size_t)b * 800,   tid, fullh);
        histf_level<  52,   4160>(p.lg[3] + (size_t)b * NC * 208,   p.ct[3] + (size_t)b * 208,   tid, fullh);
        histf_level<  14,   1120>(p.lg[4] + (size_t)b * NC * 56,    p.ct[4] + (size_t)b * 56,    tid, fullh);
        __syncthreads();
        if (tid == 0) {
            unsigned run = 0; int Tf = 0;
            for (int i = NBINS - 1; i >= 0; --i) {
                run += fullh[i];
                if (run >= TOPK) { Tf = i; break; }
            }
            s_T = Tf;
        }
        __syncthreads();
    }
    if (tid == 0) T[b] = (unsigned)s_T;
}

// ---------------- pass 2: recompute-compact exact keys (x2-unrolled) --------
#define CD_J(J, X, CT, NB0, CC, F, K)                                         \
    if ((X) > xpre) {                                                         \
        float cls = 1.0f / (1.0f + expf(-(X)));                               \
        if (cls > 0.05f) {                                                    \
            float cen = 1.0f / (1.0f + expf(-(CT)));                          \
            float comb = cls * cen;                                           \
            unsigned bits = __float_as_uint(comb);                            \
            if ((bits >> 19) >= Tb) {                                         \
                unsigned idx = (unsigned)(((NB0) + (J)) * NC + (CC));         \
                K = ((unsigned long long)bits << 32) | (0xFFFFFFFFu - idx);   \
                F = true;                                                     \
            }                                                                 \
        }                                                                     \
    }

template<int HW4, int NF4, int LVOFF>
__device__ __forceinline__ void compact_level(const float* lgb, const float* ctb,
        int tid, int lane, int bx, int gx, unsigned Tb, float xpre,
        unsigned* cntb, unsigned long long* selb, unsigned long long ltmask) {
    for (int i0 = bx * 512; i0 < NF4; i0 += gx * 512) {
        int ia = i0 + tid, ib2 = i0 + 256 + tid;
        bool la = ia < NF4, lb2 = ib2 < NF4;
        float4 va = make_float4(-9.f, -9.f, -9.f, -9.f);
        float4 vb = make_float4(-9.f, -9.f, -9.f, -9.f);
        int hwa = 0, hwb = 0, cca = 0, ccb = 0;
        if (la) {
            cca = ia / HW4; hwa = ia - cca * HW4;
            va = *(const float4*)(lgb + cca * (HW4 * 4) + hwa * 4);
        }
        if (lb2) {
            ccb = ib2 / HW4; hwb = ib2 - ccb * HW4;
            vb = *(const float4*)(lgb + ccb * (HW4 * 4) + hwb * 4);
        }
        // chunk A
        {
            bool f0 = false, f1 = false, f2 = false, f3 = false;
            unsigned long long k0 = 0, k1 = 0, k2 = 0, k3 = 0;
            if (va.x > xpre || va.y > xpre || va.z > xpre || va.w > xpre) {
                float4 cv = *(const float4*)(ctb + hwa * 4);
                int nb0 = LVOFF + hwa * 4;
                CD_J(0, va.x, cv.x, nb0, cca, f0, k0)
                CD_J(1, va.y, cv.y, nb0, cca, f1, k1)
                CD_J(2, va.z, cv.z, nb0, cca, f2, k2)
                CD_J(3, va.w, cv.w, nb0, cca, f3, k3)
            }
            unsigned long long m0 = __ballot(f0), m1 = __ballot(f1);
            unsigned long long m2 = __ballot(f2), m3 = __ballot(f3);
            if (m0 | m1 | m2 | m3) {
                unsigned t0 = (unsigned)__popcll(m0), t1 = (unsigned)__popcll(m1);
                unsigned t2 = (unsigned)__popcll(m2), t3 = (unsigned)__popcll(m3);
                int basep = 0;
                if (lane == 0) basep = (int)atomicAdd(cntb, t0 + t1 + t2 + t3);
                basep = __shfl(basep, 0);
                if (f0) { int pos = basep + (int)__popcll(m0 & ltmask);                       if (pos < CAP) selb[pos] = k0; }
                if (f1) { int pos = basep + (int)t0 + (int)__popcll(m1 & ltmask);             if (pos < CAP) selb[pos] = k1; }
                if (f2) { int pos = basep + (int)(t0 + t1) + (int)__popcll(m2 & ltmask);      if (pos < CAP) selb[pos] = k2; }
                if (f3) { int pos = basep + (int)(t0 + t1 + t2) + (int)__popcll(m3 & ltmask); if (pos < CAP) selb[pos] = k3; }
            }
        }
        // chunk B
        {
            bool f0 = false, f1 = false, f2 = false, f3 = false;
            unsigned long long k0 = 0, k1 = 0, k2 = 0, k3 = 0;
            if (vb.x > xpre || vb.y > xpre || vb.z > xpre || vb.w > xpre) {
                float4 cv = *(const float4*)(ctb + hwb * 4);
                int nb0 = LVOFF + hwb * 4;
                CD_J(0, vb.x, cv.x, nb0, ccb, f0, k0)
                CD_J(1, vb.y, cv.y, nb0, ccb, f1, k1)
                CD_J(2, vb.z, cv.z, nb0, ccb, f2, k2)
                CD_J(3, vb.w, cv.w, nb0, ccb, f3, k3)
            }
            unsigned long long m0 = __ballot(f0), m1 = __ballot(f1);
            unsigned long long m2 = __ballot(f2), m3 = __ballot(f3);
            if (m0 | m1 | m2 | m3) {
                unsigned t0 = (unsigned)__popcll(m0), t1 = (unsigned)__popcll(m1);
                unsigned t2 = (unsigned)__popcll(m2), t3 = (unsigned)__popcll(m3);
                int basep = 0;
                if (lane == 0) basep = (int)atomicAdd(cntb, t0 + t1 + t2 + t3);
                basep = __shfl(basep, 0);
                if (f0) { int pos = basep + (int)__popcll(m0 & ltmask);                       if (pos < CAP) selb[pos] = k0; }
                if (f1) { int pos = basep + (int)t0 + (int)__popcll(m1 & ltmask);             if (pos < CAP) selb[pos] = k1; }
                if (f2) { int pos = basep + (int)(t0 + t1) + (int)__popcll(m2 & ltmask);      if (pos < CAP) selb[pos] = k2; }
                if (f3) { int pos = basep + (int)(t0 + t1 + t2) + (int)__popcll(m3 & ltmask); if (pos < CAP) selb[pos] = k3; }
            }
        }
    }
}
#undef CD_J

__global__ void __launch_bounds__(256) k_compactB(Ptrs p, const unsigned* T,
                                                  unsigned* cnt2, unsigned long long* sel) {
    int b = blockIdx.y, tid = threadIdx.x, lane = tid & 63;
    int bx = blockIdx.x, gx = gridDim.x;
    unsigned Tb = T[b];
    // logit-space prefilter: bin >= T => comb >= m => cls > m => x > logit(m).
    float mthr = __uint_as_float(Tb << 19);
    float xpre = -2.95f;
    if (mthr > 1e-37f && mthr < 1.0f) {
        float lm = logf(mthr / (1.0f - mthr)) - 0.01f;
        if (lm > xpre) xpre = lm;
    }
    unsigned long long ltmask = (1ULL << lane) - 1ULL;
    unsigned* cntb = cnt2 + (size_t)b * CNTSTRIDE;
    unsigned long long* selb = sel + (size_t)b * CAP;
    compact_level<3200, 256000,     0>(p.lg[0] + (size_t)b * NC * 12800, p.ct[0] + (size_t)b * 12800, tid, lane, bx, gx, Tb, xpre, cntb, selb, ltmask);
    compact_level< 800,  64000, 12800>(p.lg[1] + (size_t)b * NC * 3200,  p.ct[1] + (size_t)b * 3200,  tid, lane, bx, gx, Tb, xpre, cntb, selb, ltmask);
    compact_level< 200,  16000, 16000>(p.lg[2] + (size_t)b * NC * 800,   p.ct[2] + (size_t)b * 800,   tid, lane, bx, gx, Tb, xpre, cntb, selb, ltmask);
    compact_level<  52,   4160, 16800>(p.lg[3] + (size_t)b * NC * 208,   p.ct[3] + (size_t)b * 208,   tid, lane, bx, gx, Tb, xpre, cntb, selb, ltmask);
    compact_level<  14,   1120, 17008>(p.lg[4] + (size_t)b * NC * 56,    p.ct[4] + (size_t)b * 56,    tid, lane, bx, gx, Tb, xpre, cntb, selb, ltmask);
}

// ---------------- rank + decode (distributed across CUs) --------------------
__global__ void __launch_bounds__(256) k_rankdec(Ptrs p, const unsigned* cnt,
                                                 const unsigned long long* sel,
                                                 const float* im_info, float* cand) {
    __shared__ __align__(16) unsigned long long keys[CAP];
    int b = blockIdx.y, tid = threadIdx.x;
    unsigned M = cnt[(size_t)b * CNTSTRIDE];
    if (M > CAP) M = CAP;
    int s0 = blockIdx.x * 256;
    if (s0 >= (int)M) return;
    int Mpad = (int)((M + 1u) & ~1u);
    for (int i = tid; i < Mpad; i += 256)
        keys[i] = (i < (int)M) ? sel[(size_t)b * CAP + i] : 0ULL;
    __syncthreads();

    int s = s0 + tid;
    if (s >= (int)M) return;
    unsigned long long k = keys[s];
    int rank = 0;
    for (int j = 0; j < Mpad; j += 2) {
        ulonglong2 kk = *(const ulonglong2*)&keys[j];   // wave-broadcast b128
        rank += (kk.x > k) ? 1 : 0;
        rank += (kk.y > k) ? 1 : 0;
    }
    if (rank >= TOPK) return;

    float Him = im_info[b * 2 + 0], Wim = im_info[b * 2 + 1];
    float xmax = Wim - 1.0f, ymax = Him - 1.0f;
    unsigned sb = (unsigned)(k >> 32);
    unsigned idx = 0xFFFFFFFFu - (unsigned)(k & 0xFFFFFFFFu);
    float val = __uint_as_float(sb);
    int n = idx / NC, c = idx - n * NC;
    int l, hw, W, stride, half, HW;
    level_of(n, l, hw, W, stride, half, HW);
    int wx = hw % W, hy = hw / W;
    float locx = (float)(wx * stride + half);
    float locy = (float)(hy * stride + half);
    const float* bb = p.bb[l] + (size_t)b * 4 * HW + hw;
    float r0 = bb[0], r1 = bb[(size_t)HW], r2 = bb[(size_t)2 * HW], r3 = bb[(size_t)3 * HW];
    float x1 = locx - r0, y1 = locy - r1, x2 = locx + r2, y2 = locy + r3;
    x1 = fminf(fmaxf(x1, 0.f), xmax);
    y1 = fminf(fmaxf(y1, 0.f), ymax);
    x2 = fminf(fmaxf(x2, 0.f), xmax);
    y2 = fminf(fmaxf(y2, 0.f), ymax);
    float scv = sqrtf(val + 1e-12f);
    float off = (float)c * 10000.0f;
    float a0 = x1 + off, a1 = y1 + off, a2 = x2 + off, a3 = y2 + off;
    float area = fmaxf(a2 - a0, 0.f) * fmaxf(a3 - a1, 0.f);
    float* dst = cand + ((size_t)b * TOPK + rank) * 12;
    *(float4*)(dst + 0) = make_float4(x1, y1, x2, y2);
    *(float4*)(dst + 4) = make_float4(a0, a1, a2, a3);
    *(float4*)(dst + 8) = make_float4(area, scv, (float)c, 0.f);
}

// ---------------- scan-NMS (one wave per batch) -----------------------------
__global__ void __launch_bounds__(64) k_nms(const unsigned* cnt, const float* cand,
                                            float* out) {
    __shared__ float4 s_ob[CHUNK], s_nb[CHUNK], s_ms[CHUNK];
    int b = blockIdx.x, lane = threadIdx.x;
    unsigned M = cnt[(size_t)b * CNTSTRIDE];
    if (M > CAP) M = CAP;
    int ncand = (int)M < TOPK ? (int)M : TOPK;
    const float* src = cand + (size_t)b * TOPK * 12;
    float* ob = out + (size_t)b * MAXDET * 6;

    int na = 0;
    float4 a0b = make_float4(0.f, 0.f, 0.f, 0.f);
    float4 a1b = make_float4(0.f, 0.f, 0.f, 0.f);
    float a0a = 0.f, a1a = 0.f;

    for (int base = 0; base < ncand && na < MAXDET; base += CHUNK) {
        int cn = ncand - base; if (cn > CHUNK) cn = CHUNK;
        for (int cidx = lane; cidx < cn; cidx += 64) {
            const float* s = src + (size_t)(base + cidx) * 12;
            s_ob[cidx] = *(const float4*)(s + 0);
            s_nb[cidx] = *(const float4*)(s + 4);
            s_ms[cidx] = *(const float4*)(s + 8);
        }
        __syncthreads();
        for (int r = 0; r < cn && na < MAXDET; ++r) {
            float4 cb = s_nb[r];
            float ca = s_ms[r].x;
            bool sup = false;
            if (lane < na) {
                float xx1 = fmaxf(a0b.x, cb.x);
                float yy1 = fmaxf(a0b.y, cb.y);
                float xx2 = fminf(a0b.z, cb.z);
                float yy2 = fminf(a0b.w, cb.w);
                float inter = fmaxf(xx2 - xx1, 0.f) * fmaxf(yy2 - yy1, 0.f);
                float iou = inter / (((a0a + ca) - inter) + 1e-9f);
                sup = (iou >= 0.6f);
            }
            if (lane + 64 < na) {
                float xx1 = fmaxf(a1b.x, cb.x);
                float yy1 = fmaxf(a1b.y, cb.y);
                float xx2 = fminf(a1b.z, cb.z);
                float yy2 = fminf(a1b.w, cb.w);
                float inter = fmaxf(xx2 - xx1, 0.f) * fmaxf(yy2 - yy1, 0.f);
                float iou = inter / (((a1a + ca) - inter) + 1e-9f);
                sup |= (iou >= 0.6f);
            }
            if (__ballot(sup) == 0ULL) {
                if (lane == (na & 63)) {
                    if (na < 64) { a0b = cb; a0a = ca; }
                    else         { a1b = cb; a1a = ca; }
                }
                if (lane == 0) {
                    float4 o4 = s_ob[r]; float4 m4 = s_ms[r];
                    ob[na * 6 + 0] = o4.x; ob[na * 6 + 1] = o4.y;
                    ob[na * 6 + 2] = o4.z; ob[na * 6 + 3] = o4.w;
                    ob[na * 6 + 4] = m4.y; ob[na * 6 + 5] = m4.z;
                }
                ++na;
            }
        }
        __syncthreads();
    }
    for (int q = na * 6 + lane; q < MAXDET * 6; q += 64)
        ob[q] = 0.f;
}

extern "C" void kernel_launch(void* const* d_in, const int* in_sizes, int n_in,
                              void* d_out, int out_size, void* d_ws, size_t ws_size,
                              hipStream_t stream) {
    Ptrs p;
    for (int l = 0; l < 5; ++l) {
        p.lg[l] = (const float*)d_in[3 * l + 0];
        p.bb[l] = (const float*)d_in[3 * l + 1];
        p.ct[l] = (const float*)d_in[3 * l + 2];
    }
    const float* im_info = (const float*)d_in[15];
    float* out = (float*)d_out;
    unsigned char* w = (unsigned char*)d_ws;

    // layout: hist 16*128*64*4 = 524288 | cnt2 4096 | T 256 | sel 524288 |
    //         cand 768000  -> total 1,820,928 B. No memset: hist slots are
    //         written unconditionally, cnt2 zeroed by k_histB.
    unsigned* hist          = (unsigned*)(w);
    unsigned* cnt2          = (unsigned*)(w + 524288);
    unsigned* T             = (unsigned*)(w + 528384);
    unsigned long long* sel = (unsigned long long*)(w + 528640);
    float* cand             = (float*)(w + 1052928);

    k_histB<<<dim3(GH, NB), 256, 0, stream>>>(p, hist, cnt2);
    k_thresh<<<NB, 256, 0, stream>>>(p, hist, T);
    k_compactB<<<dim3(GH, NB), 256, 0, stream>>>(p, T, cnt2, sel);
    k_rankdec<<<dim3(16, NB), 256, 0, stream>>>(p, cnt2, sel, im_info, cand);
    k_nms<<<NB, 64, 0, stream>>>(cnt2, cand, out);
}